// Round 6
// baseline (251.127 us; speedup 1.0000x reference)
//
#include <hip/hip_runtime.h>
#include <math.h>

#define EMBED 512
#define HDIM 64
#define NHEADS 8
#define SEQ_N 2048
#define SEQ_L 2048
#define BATCH 4
#define MROWS (SEQ_N*BATCH)   // 8192 rows, row index m = n*BATCH + b
#define BE (BATCH*EMBED)      // 2048 element row stride in (n,b,E) tensors

// scores scale folded into Q-projection and pe1: 1/sqrt(64) * log2(e)
#define QSCALE 0.18033688f

typedef _Float16 f16;
typedef _Float16 half8 __attribute__((ext_vector_type(8)));
typedef _Float16 half4 __attribute__((ext_vector_type(4)));
typedef _Float16 half2v __attribute__((ext_vector_type(2)));
typedef float floatx4 __attribute__((ext_vector_type(4)));
typedef float floatx16 __attribute__((ext_vector_type(16)));

static __device__ inline float fast_exp2(float x) {
#if __has_builtin(__builtin_amdgcn_exp2f)
  return __builtin_amdgcn_exp2f(x);
#else
  return __expf(x * 0.69314718056f);
#endif
}

static __device__ inline half2v pk2(float a, float b) {
#if __has_builtin(__builtin_amdgcn_cvt_pkrtz)
  return __builtin_bit_cast(half2v, __builtin_amdgcn_cvt_pkrtz(a, b));
#else
  half2v o; o[0] = (f16)a; o[1] = (f16)b; return o;
#endif
}

// pack 8 fp32 -> half8 (for fp32->f16 in-register staging)
static __device__ inline half8 cvt8(const float4& a, const float4& b) {
  half2v p0 = pk2(a.x, a.y), p1 = pk2(a.z, a.w);
  half2v p2 = pk2(b.x, b.y), p3 = pk2(b.z, b.w);
  half8 o;
  o[0] = p0[0]; o[1] = p0[1]; o[2] = p1[0]; o[3] = p1[1];
  o[4] = p2[0]; o[5] = p2[1]; o[6] = p3[0]; o[7] = p3[1];
  return o;
}

// ---------------------------------------- fused QKV projection GEMM (128x128)
// Reads fp32 activations + fp32 weights, converts in-register while staging
// (replaces the old cvt_all pass entirely). blockIdx.y in [0,12):
// sel = y>>2 picks {q,k,v}; n0 = (y&3)*128. sel==0 output pre-scaled QSCALE;
// sel==2 V stored TRANSPOSED per head into vt[((b*8+h)*64+d)*2048 + l].
__global__ __launch_bounds__(256) void gemm_qkv(const float* __restrict__ A0,
                                                const float* __restrict__ A1,
                                                const float* __restrict__ A2,
                                                const float* __restrict__ W0,
                                                const float* __restrict__ W1,
                                                const float* __restrict__ W2,
                                                const float* __restrict__ b0,
                                                const float* __restrict__ b1,
                                                const float* __restrict__ b2,
                                                f16* __restrict__ C0, f16* __restrict__ C1,
                                                f16* __restrict__ C2t) {
  __shared__ alignas(16) f16 As[128 * 40];
  __shared__ alignas(16) f16 Bs[128 * 40];
  const int sel = blockIdx.y >> 2;
  const float* A = sel == 0 ? A0 : sel == 1 ? A1 : A2;
  const float* Bt = sel == 0 ? W0 : sel == 1 ? W1 : W2;
  const float* bias = sel == 0 ? b0 : sel == 1 ? b1 : b2;
  const float scl = sel == 0 ? QSCALE : 1.0f;
  const int tid = threadIdx.x;
  const int wave = tid >> 6, lane = tid & 63, quad = lane >> 4, l16 = lane & 15;
  const int wm = wave & 1, wn = wave >> 1;
  const long m0 = (long)blockIdx.x * 128;
  const long n0 = (long)(blockIdx.y & 3) * 128;
  floatx4 acc[4][4] = {};
  const int r0 = tid >> 2;        // 0..63
  const int c0 = (tid & 3) * 8;   // 0,8,16,24 (fp32 elements)

  for (int k0 = 0; k0 < EMBED; k0 += 32) {
    __syncthreads();
    float4 a00 = *reinterpret_cast<const float4*>(A + (m0 + r0) * EMBED + k0 + c0);
    float4 a01 = *reinterpret_cast<const float4*>(A + (m0 + r0) * EMBED + k0 + c0 + 4);
    float4 a10 = *reinterpret_cast<const float4*>(A + (m0 + r0 + 64) * EMBED + k0 + c0);
    float4 a11 = *reinterpret_cast<const float4*>(A + (m0 + r0 + 64) * EMBED + k0 + c0 + 4);
    float4 w00 = *reinterpret_cast<const float4*>(Bt + (n0 + r0) * EMBED + k0 + c0);
    float4 w01 = *reinterpret_cast<const float4*>(Bt + (n0 + r0) * EMBED + k0 + c0 + 4);
    float4 w10 = *reinterpret_cast<const float4*>(Bt + (n0 + r0 + 64) * EMBED + k0 + c0);
    float4 w11 = *reinterpret_cast<const float4*>(Bt + (n0 + r0 + 64) * EMBED + k0 + c0 + 4);
    *reinterpret_cast<half8*>(&As[r0 * 40 + c0]) = cvt8(a00, a01);
    *reinterpret_cast<half8*>(&As[(r0 + 64) * 40 + c0]) = cvt8(a10, a11);
    *reinterpret_cast<half8*>(&Bs[r0 * 40 + c0]) = cvt8(w00, w01);
    *reinterpret_cast<half8*>(&Bs[(r0 + 64) * 40 + c0]) = cvt8(w10, w11);
    __syncthreads();
    half8 af[4], bf[4];
#pragma unroll
    for (int i = 0; i < 4; ++i)
      af[i] = *reinterpret_cast<const half8*>(&As[(wm * 64 + i * 16 + l16) * 40 + quad * 8]);
#pragma unroll
    for (int j = 0; j < 4; ++j)
      bf[j] = *reinterpret_cast<const half8*>(&Bs[(wn * 64 + j * 16 + l16) * 40 + quad * 8]);
#pragma unroll
    for (int i = 0; i < 4; ++i)
#pragma unroll
      for (int j = 0; j < 4; ++j)
        acc[i][j] = __builtin_amdgcn_mfma_f32_16x16x32_f16(af[i], bf[j], acc[i][j], 0, 0, 0);
  }
#pragma unroll
  for (int i = 0; i < 4; ++i)
#pragma unroll
    for (int r = 0; r < 4; ++r) {
      long row = m0 + wm * 64 + i * 16 + quad * 4 + r;
#pragma unroll
      for (int j = 0; j < 4; ++j) {
        long col = n0 + wn * 64 + j * 16 + l16;
        float val = (acc[i][j][r] + bias[col]) * scl;
        if (sel == 2) {
          long bq = row & 3, ltok = row >> 2;
          long hh = col >> 6, dd = col & 63;
          C2t[(((bq << 3) + hh) * 64 + dd) * 2048 + ltok] = (f16)val;
        } else {
          f16* C = sel == 0 ? C0 : C1;
          C[row * EMBED + col] = (f16)val;
        }
      }
    }
}

// ------------------------------------- output GEMM (128x64, fp32 W + fp32 out)
__global__ __launch_bounds__(256) void gemm_out(const f16* __restrict__ A,
                                                const float* __restrict__ Wt,
                                                const float* __restrict__ bias,
                                                float* __restrict__ C) {
  __shared__ alignas(16) f16 As[128 * 40];
  __shared__ alignas(16) f16 Bs[64 * 40];
  const int tid = threadIdx.x;
  const int wave = tid >> 6, lane = tid & 63, quad = lane >> 4, l16 = lane & 15;
  const long m0 = (long)blockIdx.x * 128;
  const long n0 = (long)blockIdx.y * 64;
  floatx4 acc[2][4] = {};
  const int r0 = tid >> 2;
  const int c0 = (tid & 3) * 8;

  for (int k0 = 0; k0 < EMBED; k0 += 32) {
    __syncthreads();
    uint4 a0 = *reinterpret_cast<const uint4*>(A + (m0 + r0) * EMBED + k0 + c0);
    uint4 a1 = *reinterpret_cast<const uint4*>(A + (m0 + r0 + 64) * EMBED + k0 + c0);
    float4 w0 = *reinterpret_cast<const float4*>(Wt + (n0 + r0) * EMBED + k0 + c0);
    float4 w1 = *reinterpret_cast<const float4*>(Wt + (n0 + r0) * EMBED + k0 + c0 + 4);
    *reinterpret_cast<uint4*>(&As[r0 * 40 + c0]) = a0;
    *reinterpret_cast<uint4*>(&As[(r0 + 64) * 40 + c0]) = a1;
    *reinterpret_cast<half8*>(&Bs[r0 * 40 + c0]) = cvt8(w0, w1);
    __syncthreads();
    half8 af[2], bf[4];
#pragma unroll
    for (int i = 0; i < 2; ++i)
      af[i] = *reinterpret_cast<const half8*>(&As[(wave * 32 + i * 16 + l16) * 40 + quad * 8]);
#pragma unroll
    for (int j = 0; j < 4; ++j)
      bf[j] = *reinterpret_cast<const half8*>(&Bs[(j * 16 + l16) * 40 + quad * 8]);
#pragma unroll
    for (int i = 0; i < 2; ++i)
#pragma unroll
      for (int j = 0; j < 4; ++j)
        acc[i][j] = __builtin_amdgcn_mfma_f32_16x16x32_f16(af[i], bf[j], acc[i][j], 0, 0, 0);
  }
#pragma unroll
  for (int i = 0; i < 2; ++i)
#pragma unroll
    for (int r = 0; r < 4; ++r) {
      long row = m0 + wave * 32 + i * 16 + quad * 4 + r;
#pragma unroll
      for (int j = 0; j < 4; ++j) {
        long col = n0 + j * 16 + l16;
        C[row * EMBED + col] = acc[i][j][r] + bias[col];
      }
    }
}

// ------------------------------------------------------------- flash attention
// grid = (N/128, B*H), 256 threads = 4 waves, wave owns 32 Q-rows.
// S^T = [K|pe2].[Q|pe1*sc]^T via mfma_32x32x16 -> P in C-layout feeds
// mfma_32x32x8 B-operand straight from registers (no LDS round-trip).
// Round 5/6: register-prefetch double buffering of the K/V staging (load chunk
// c+1 into VGPRs before computing chunk c) + PV accumulator split by t-parity
// to break the dependent-MFMA chain.
#define KST 88    // Ks/Qs row stride (f16)
#define VST 136   // Vt row stride (f16)
#define NCHUNK (SEQ_L / 128)
__global__ __launch_bounds__(256, 2) void attn_flash(const f16* __restrict__ qp,
                                                     const f16* __restrict__ kp,
                                                     const f16* __restrict__ vt,
                                                     const float* __restrict__ pe1,
                                                     const float* __restrict__ pe2,
                                                     f16* __restrict__ ao) {
  __shared__ alignas(16) f16 Qs[128 * KST];
  __shared__ alignas(16) f16 Ks[128 * KST];
  __shared__ alignas(16) f16 Vt[64 * VST];
  const int tid = threadIdx.x, wave = tid >> 6, lane = tid & 63;
  const int m = lane & 31, h = lane >> 5;
  const int n0 = blockIdx.x * 128;
  const int b = blockIdx.y >> 3, hd = blockIdx.y & 7;
  const long headoff = (long)b * EMBED + hd * HDIM;
  const long vhead = (long)blockIdx.y * 64 * 2048;

  // ---- one-time staging: Q tile, pe1, zero pads of Qs/Ks cols 68..87
  for (int c = tid; c < 1024; c += 256) {
    int r = c >> 3, col = (c & 7) * 8;
    *reinterpret_cast<uint4*>(&Qs[r * KST + col]) =
        *reinterpret_cast<const uint4*>(qp + (long)(n0 + r) * BE + headoff + col);
  }
  const uint4 z4 = {0, 0, 0, 0};
  const uint2 z2 = {0, 0};
  for (int c = tid; c < 512; c += 256) {
    int r = c >> 2, s = c & 3;
    if (s == 0) *reinterpret_cast<uint2*>(&Qs[r * KST + 68]) = z2;
    else if (s == 1) *reinterpret_cast<uint4*>(&Qs[r * KST + 72]) = z4;
    else if (s == 2) *reinterpret_cast<uint4*>(&Qs[r * KST + 80]) = z4;
    if (s == 0) *reinterpret_cast<uint2*>(&Ks[r * KST + 68]) = z2;
    else if (s == 1) *reinterpret_cast<uint4*>(&Ks[r * KST + 72]) = z4;
    else if (s == 2) *reinterpret_cast<uint4*>(&Ks[r * KST + 80]) = z4;
  }
  if (tid < 128) {
    long base = ((long)b * SEQ_N + n0 + tid) * 3;
    half4 v8;
    v8[0] = (f16)(pe1[base + 0] * QSCALE);
    v8[1] = (f16)(pe1[base + 1] * QSCALE);
    v8[2] = (f16)(pe1[base + 2] * QSCALE);
    v8[3] = (f16)0.f;
    *reinterpret_cast<half4*>(&Qs[tid * KST + 64]) = v8;
  }

  // ---- prefetch registers and chunk load/store helpers
  uint4 kr[4], vr[4];
  float p2a = 0.f, p2b = 0.f, p2c = 0.f;
  auto load_chunk = [&](int l0) {
#pragma unroll
    for (int i = 0; i < 4; ++i) {
      int idx = tid + i * 256;
      int r = idx >> 3, col = (idx & 7) * 8;
      kr[i] = *reinterpret_cast<const uint4*>(kp + (long)(l0 + r) * BE + headoff + col);
      int rv = idx >> 4, cv = (idx & 15) * 8;
      vr[i] = *reinterpret_cast<const uint4*>(vt + vhead + (long)rv * 2048 + l0 + cv);
    }
    if (tid < 128) {
      long bb = (long)(l0 + tid) * 3;
      p2a = pe2[bb + 0]; p2b = pe2[bb + 1]; p2c = pe2[bb + 2];
    }
  };
  auto store_chunk = [&]() {
#pragma unroll
    for (int i = 0; i < 4; ++i) {
      int idx = tid + i * 256;
      int r = idx >> 3, col = (idx & 7) * 8;
      *reinterpret_cast<uint4*>(&Ks[r * KST + col]) = kr[i];
      int rv = idx >> 4, cv = (idx & 15) * 8;
      *reinterpret_cast<uint4*>(&Vt[rv * VST + cv]) = vr[i];
    }
    if (tid < 128) {
      half4 p2;
      p2[0] = (f16)p2a; p2[1] = (f16)p2b; p2[2] = (f16)p2c; p2[3] = (f16)0.f;
      *reinterpret_cast<half4*>(&Ks[tid * KST + 64]) = p2;
    }
  };

  load_chunk(0);
  __syncthreads();  // Q/pe1/pad writes visible
  half8 qf[5];
#pragma unroll
  for (int e = 0; e < 5; ++e)
    qf[e] = *reinterpret_cast<const half8*>(&Qs[(wave * 32 + m) * KST + e * 16 + h * 8]);
  store_chunk();    // chunk 0 -> LDS

  floatx16 oacc[2][2] = {};   // [dt][t&1] — parity split breaks the MFMA chain
  float lp0 = 0.f, lp1 = 0.f;

#pragma unroll 1
  for (int c = 0; c < NCHUNK; ++c) {
    if (c + 1 < NCHUNK) load_chunk((c + 1) * 128);  // prefetch into regs
    __syncthreads();  // chunk c LDS writes complete (from prev iter / preamble)
#pragma unroll
    for (int t = 0; t < 4; ++t) {
      floatx16 st = {};
#pragma unroll
      for (int e = 0; e < 5; ++e) {
        half8 kf = *reinterpret_cast<const half8*>(&Ks[(t * 32 + m) * KST + e * 16 + h * 8]);
        st = __builtin_amdgcn_mfma_f32_32x32x16_f16(kf, qf[e], st, 0, 0, 0);
      }
      float p[16];
#pragma unroll
      for (int r = 0; r < 16; ++r) p[r] = fast_exp2(st[r]);
#pragma unroll
      for (int r = 0; r < 16; r += 2) { lp0 += p[r]; lp1 += p[r + 1]; }
#pragma unroll
      for (int s = 0; s < 4; ++s) {
        half2v u0 = pk2(p[4 * s + 0], p[4 * s + 1]);
        half2v u1 = pk2(p[4 * s + 2], p[4 * s + 3]);
        half4 bp;
        bp[0] = u0[0]; bp[1] = u0[1]; bp[2] = u1[0]; bp[3] = u1[1];
        int lcol = t * 32 + s * 8 + h * 4;
#pragma unroll
        for (int dt = 0; dt < 2; ++dt) {
          half4 vf = *reinterpret_cast<const half4*>(&Vt[(dt * 32 + m) * VST + lcol]);
          oacc[dt][t & 1] = __builtin_amdgcn_mfma_f32_32x32x8f16(vf, bp, oacc[dt][t & 1], 0, 0, 0);
        }
      }
    }
    if (c + 1 < NCHUNK) {
      __syncthreads();  // all reads of chunk c done
      store_chunk();    // regs -> LDS (chunk c+1)
    }
  }

  float lpart = lp0 + lp1;
  lpart += __shfl_xor(lpart, 32);  // lane^32 holds the other l-half of same q
  float inv = 1.f / lpart;
  long qrow = n0 + wave * 32 + m;
#pragma unroll
  for (int dt = 0; dt < 2; ++dt)
#pragma unroll
    for (int g = 0; g < 4; ++g) {
      half4 o4;
#pragma unroll
      for (int x = 0; x < 4; ++x) {
        float o = oacc[dt][0][4 * g + x] + oacc[dt][1][4 * g + x];
        o4[x] = (f16)(o * inv);
      }
      int d = dt * 32 + 8 * g + 4 * h;
      *reinterpret_cast<half4*>(ao + qrow * BE + headoff + d) = o4;
    }
}

// ---------------------------------------------------------------------- launch
extern "C" void kernel_launch(void* const* d_in, const int* in_sizes, int n_in,
                              void* d_out, int out_size, void* d_ws, size_t ws_size,
                              hipStream_t stream) {
  const float* q   = (const float*)d_in[0];
  const float* k   = (const float*)d_in[1];
  const float* v   = (const float*)d_in[2];
  const float* pe1 = (const float*)d_in[3];
  const float* pe2 = (const float*)d_in[4];
  const float* Wq  = (const float*)d_in[5];
  const float* bq  = (const float*)d_in[6];
  const float* Wk  = (const float*)d_in[7];
  const float* bk  = (const float*)d_in[8];
  const float* Wv  = (const float*)d_in[9];
  const float* bv  = (const float*)d_in[10];
  const float* Wo  = (const float*)d_in[11];
  const float* bo  = (const float*)d_in[12];
  float* out = (float*)d_out;

  f16* ws = (f16*)d_ws;
  const long TOK = (long)MROWS * EMBED;  // 4,194,304 elements
  f16* qpb = ws;
  f16* kpb = qpb + TOK;
  f16* vtb = kpb + TOK;   // transposed-V (written by gemm_qkv sel==2)
  f16* aob = vtb + TOK;   // ~32 MB total

  gemm_qkv<<<dim3(MROWS / 128, 12), 256, 0, stream>>>(q, k, v, Wq, Wk, Wv,
                                                      bq, bk, bv, qpb, kpb, vtb);

  attn_flash<<<dim3(SEQ_N / 128, BATCH * NHEADS), 256, 0, stream>>>(qpb, kpb, vtb, pe1, pe2, aob);

  gemm_out<<<dim3(MROWS / 128, EMBED / 64), 256, 0, stream>>>(aob, Wo, bo, out);
}

// Round 7
// 212.820 us; speedup vs baseline: 1.1800x; 1.1800x over previous
//
#include <hip/hip_runtime.h>
#include <math.h>

#define EMBED 512
#define HDIM 64
#define NHEADS 8
#define SEQ_N 2048
#define SEQ_L 2048
#define BATCH 4
#define MROWS (SEQ_N*BATCH)   // 8192 rows, row index m = n*BATCH + b
#define BE (BATCH*EMBED)      // 2048 element row stride in (n,b,E) tensors

// scores scale folded into Q-projection and pe1: 1/sqrt(64) * log2(e)
#define QSCALE 0.18033688f

typedef _Float16 f16;
typedef _Float16 half8 __attribute__((ext_vector_type(8)));
typedef _Float16 half4 __attribute__((ext_vector_type(4)));
typedef _Float16 half2v __attribute__((ext_vector_type(2)));
typedef float floatx4 __attribute__((ext_vector_type(4)));
typedef float floatx16 __attribute__((ext_vector_type(16)));

static __device__ inline float fast_exp2(float x) {
#if __has_builtin(__builtin_amdgcn_exp2f)
  return __builtin_amdgcn_exp2f(x);
#else
  return __expf(x * 0.69314718056f);
#endif
}

static __device__ inline half2v pk2(float a, float b) {
#if __has_builtin(__builtin_amdgcn_cvt_pkrtz)
  return __builtin_bit_cast(half2v, __builtin_amdgcn_cvt_pkrtz(a, b));
#else
  half2v o; o[0] = (f16)a; o[1] = (f16)b; return o;
#endif
}

// pack 8 fp32 -> half8 (for fp32->f16 in-register staging)
static __device__ inline half8 cvt8(const float4& a, const float4& b) {
  half2v p0 = pk2(a.x, a.y), p1 = pk2(a.z, a.w);
  half2v p2 = pk2(b.x, b.y), p3 = pk2(b.z, b.w);
  half8 o;
  o[0] = p0[0]; o[1] = p0[1]; o[2] = p1[0]; o[3] = p1[1];
  o[4] = p2[0]; o[5] = p2[1]; o[6] = p3[0]; o[7] = p3[1];
  return o;
}

// ---------------------------------------- fused QKV projection GEMM (128x128)
// Reads fp32 activations + fp32 weights, converts in-register while staging.
// blockIdx.y in [0,12): sel = y>>2 picks {q,k,v}; n0 = (y&3)*128.
// sel==0 output pre-scaled QSCALE; sel==2 V stored TRANSPOSED per head into
// vt[((b*8+h)*64+d)*2048 + l].
__global__ __launch_bounds__(256) void gemm_qkv(const float* __restrict__ A0,
                                                const float* __restrict__ A1,
                                                const float* __restrict__ A2,
                                                const float* __restrict__ W0,
                                                const float* __restrict__ W1,
                                                const float* __restrict__ W2,
                                                const float* __restrict__ b0,
                                                const float* __restrict__ b1,
                                                const float* __restrict__ b2,
                                                f16* __restrict__ C0, f16* __restrict__ C1,
                                                f16* __restrict__ C2t) {
  __shared__ alignas(16) f16 As[128 * 40];
  __shared__ alignas(16) f16 Bs[128 * 40];
  const int sel = blockIdx.y >> 2;
  const float* A = sel == 0 ? A0 : sel == 1 ? A1 : A2;
  const float* Bt = sel == 0 ? W0 : sel == 1 ? W1 : W2;
  const float* bias = sel == 0 ? b0 : sel == 1 ? b1 : b2;
  const float scl = sel == 0 ? QSCALE : 1.0f;
  const int tid = threadIdx.x;
  const int wave = tid >> 6, lane = tid & 63, quad = lane >> 4, l16 = lane & 15;
  const int wm = wave & 1, wn = wave >> 1;
  const long m0 = (long)blockIdx.x * 128;
  const long n0 = (long)(blockIdx.y & 3) * 128;
  floatx4 acc[4][4] = {};
  const int r0 = tid >> 2;        // 0..63
  const int c0 = (tid & 3) * 8;   // 0,8,16,24 (fp32 elements)

  for (int k0 = 0; k0 < EMBED; k0 += 32) {
    __syncthreads();
    float4 a00 = *reinterpret_cast<const float4*>(A + (m0 + r0) * EMBED + k0 + c0);
    float4 a01 = *reinterpret_cast<const float4*>(A + (m0 + r0) * EMBED + k0 + c0 + 4);
    float4 a10 = *reinterpret_cast<const float4*>(A + (m0 + r0 + 64) * EMBED + k0 + c0);
    float4 a11 = *reinterpret_cast<const float4*>(A + (m0 + r0 + 64) * EMBED + k0 + c0 + 4);
    float4 w00 = *reinterpret_cast<const float4*>(Bt + (n0 + r0) * EMBED + k0 + c0);
    float4 w01 = *reinterpret_cast<const float4*>(Bt + (n0 + r0) * EMBED + k0 + c0 + 4);
    float4 w10 = *reinterpret_cast<const float4*>(Bt + (n0 + r0 + 64) * EMBED + k0 + c0);
    float4 w11 = *reinterpret_cast<const float4*>(Bt + (n0 + r0 + 64) * EMBED + k0 + c0 + 4);
    *reinterpret_cast<half8*>(&As[r0 * 40 + c0]) = cvt8(a00, a01);
    *reinterpret_cast<half8*>(&As[(r0 + 64) * 40 + c0]) = cvt8(a10, a11);
    *reinterpret_cast<half8*>(&Bs[r0 * 40 + c0]) = cvt8(w00, w01);
    *reinterpret_cast<half8*>(&Bs[(r0 + 64) * 40 + c0]) = cvt8(w10, w11);
    __syncthreads();
    half8 af[4], bf[4];
#pragma unroll
    for (int i = 0; i < 4; ++i)
      af[i] = *reinterpret_cast<const half8*>(&As[(wm * 64 + i * 16 + l16) * 40 + quad * 8]);
#pragma unroll
    for (int j = 0; j < 4; ++j)
      bf[j] = *reinterpret_cast<const half8*>(&Bs[(wn * 64 + j * 16 + l16) * 40 + quad * 8]);
#pragma unroll
    for (int i = 0; i < 4; ++i)
#pragma unroll
      for (int j = 0; j < 4; ++j)
        acc[i][j] = __builtin_amdgcn_mfma_f32_16x16x32_f16(af[i], bf[j], acc[i][j], 0, 0, 0);
  }
#pragma unroll
  for (int i = 0; i < 4; ++i)
#pragma unroll
    for (int r = 0; r < 4; ++r) {
      long row = m0 + wm * 64 + i * 16 + quad * 4 + r;
#pragma unroll
      for (int j = 0; j < 4; ++j) {
        long col = n0 + wn * 64 + j * 16 + l16;
        float val = (acc[i][j][r] + bias[col]) * scl;
        if (sel == 2) {
          long bq = row & 3, ltok = row >> 2;
          long hh = col >> 6, dd = col & 63;
          C2t[(((bq << 3) + hh) * 64 + dd) * 2048 + ltok] = (f16)val;
        } else {
          f16* C = sel == 0 ? C0 : C1;
          C[row * EMBED + col] = (f16)val;
        }
      }
    }
}

// ------------------------------------- output GEMM (128x64, fp32 W + fp32 out)
__global__ __launch_bounds__(256) void gemm_out(const f16* __restrict__ A,
                                                const float* __restrict__ Wt,
                                                const float* __restrict__ bias,
                                                float* __restrict__ C) {
  __shared__ alignas(16) f16 As[128 * 40];
  __shared__ alignas(16) f16 Bs[64 * 40];
  const int tid = threadIdx.x;
  const int wave = tid >> 6, lane = tid & 63, quad = lane >> 4, l16 = lane & 15;
  const long m0 = (long)blockIdx.x * 128;
  const long n0 = (long)blockIdx.y * 64;
  floatx4 acc[2][4] = {};
  const int r0 = tid >> 2;
  const int c0 = (tid & 3) * 8;

  for (int k0 = 0; k0 < EMBED; k0 += 32) {
    __syncthreads();
    uint4 a0 = *reinterpret_cast<const uint4*>(A + (m0 + r0) * EMBED + k0 + c0);
    uint4 a1 = *reinterpret_cast<const uint4*>(A + (m0 + r0 + 64) * EMBED + k0 + c0);
    float4 w0 = *reinterpret_cast<const float4*>(Wt + (n0 + r0) * EMBED + k0 + c0);
    float4 w1 = *reinterpret_cast<const float4*>(Wt + (n0 + r0) * EMBED + k0 + c0 + 4);
    *reinterpret_cast<uint4*>(&As[r0 * 40 + c0]) = a0;
    *reinterpret_cast<uint4*>(&As[(r0 + 64) * 40 + c0]) = a1;
    *reinterpret_cast<half8*>(&Bs[r0 * 40 + c0]) = cvt8(w0, w1);
    __syncthreads();
    half8 af[2], bf[4];
#pragma unroll
    for (int i = 0; i < 2; ++i)
      af[i] = *reinterpret_cast<const half8*>(&As[(wave * 32 + i * 16 + l16) * 40 + quad * 8]);
#pragma unroll
    for (int j = 0; j < 4; ++j)
      bf[j] = *reinterpret_cast<const half8*>(&Bs[(j * 16 + l16) * 40 + quad * 8]);
#pragma unroll
    for (int i = 0; i < 2; ++i)
#pragma unroll
      for (int j = 0; j < 4; ++j)
        acc[i][j] = __builtin_amdgcn_mfma_f32_16x16x32_f16(af[i], bf[j], acc[i][j], 0, 0, 0);
  }
#pragma unroll
  for (int i = 0; i < 2; ++i)
#pragma unroll
    for (int r = 0; r < 4; ++r) {
      long row = m0 + wave * 32 + i * 16 + quad * 4 + r;
#pragma unroll
      for (int j = 0; j < 4; ++j) {
        long col = n0 + j * 16 + l16;
        C[row * EMBED + col] = acc[i][j][r] + bias[col];
      }
    }
}

// ------------------------------------------------------------- flash attention
// grid = (N/128, B*H), 512 threads = 8 waves. Wave-pair (w, w+4) shares the
// q-strip (w&3)*32; half = w>>2 picks l-tiles {0,1} or {2,3} of each chunk.
// S^T = [K|pe2].[Q|pe1*sc]^T via mfma_32x32x16 -> P in C-layout feeds
// mfma_32x32x8 B-operand straight from registers (no LDS round-trip).
// Q is staged THROUGH Ks (dead after qf hoist); final merge of the two
// l-halves goes through LDS aliasing Ks/Vt after the last barrier.
#define KST 88    // Ks row stride (f16)
#define VST 136   // Vt row stride (f16)
#define NCHUNK (SEQ_L / 128)
#define LDSB (128 * KST * 2 + 64 * VST * 2)   // 39936 B
__global__ __launch_bounds__(512, 4) void attn_flash(const f16* __restrict__ qp,
                                                     const f16* __restrict__ kp,
                                                     const f16* __restrict__ vt,
                                                     const float* __restrict__ pe1,
                                                     const float* __restrict__ pe2,
                                                     f16* __restrict__ ao) {
  __shared__ alignas(16) unsigned char smem[LDSB];
  f16* Ks = reinterpret_cast<f16*>(smem);                       // 128 x KST
  f16* Vt = reinterpret_cast<f16*>(smem + 128 * KST * 2);       // 64 x VST
  float* comb = reinterpret_cast<float*>(smem);                 // merge region
  const int tid = threadIdx.x, wave = tid >> 6, lane = tid & 63;
  const int m = lane & 31, h = lane >> 5;
  const int strip = wave & 3, half = wave >> 2;
  const int n0 = blockIdx.x * 128;
  const int b = blockIdx.y >> 3, hd = blockIdx.y & 7;
  const long headoff = (long)b * EMBED + hd * HDIM;
  const long vhead = (long)blockIdx.y * 64 * 2048;

  // ---- stage Q (through Ks) + pe1 + zero pads, and chunk-0 V into Vt
  for (int c = tid; c < 1024; c += 512) {
    int r = c >> 3, col = (c & 7) * 8;
    *reinterpret_cast<uint4*>(&Ks[r * KST + col]) =
        *reinterpret_cast<const uint4*>(qp + (long)(n0 + r) * BE + headoff + col);
    int rv = c >> 4, cv = (c & 15) * 8;
    *reinterpret_cast<uint4*>(&Vt[rv * VST + cv]) =
        *reinterpret_cast<const uint4*>(vt + vhead + (long)rv * 2048 + 0 + cv);
  }
  {
    const uint4 z4 = {0, 0, 0, 0};
    const uint2 z2 = {0, 0};
    int r = tid >> 2, s = tid & 3;
    if (s == 0) *reinterpret_cast<uint2*>(&Ks[r * KST + 68]) = z2;
    else if (s == 1) *reinterpret_cast<uint4*>(&Ks[r * KST + 72]) = z4;
    else if (s == 2) *reinterpret_cast<uint4*>(&Ks[r * KST + 80]) = z4;
  }
  if (tid < 128) {
    long base = ((long)b * SEQ_N + n0 + tid) * 3;
    half4 v8;
    v8[0] = (f16)(pe1[base + 0] * QSCALE);
    v8[1] = (f16)(pe1[base + 1] * QSCALE);
    v8[2] = (f16)(pe1[base + 2] * QSCALE);
    v8[3] = (f16)0.f;
    *reinterpret_cast<half4*>(&Ks[tid * KST + 64]) = v8;
  }
  __syncthreads();

  // hoist Q B-frags (waves w and w+4 read the same strip — fine)
  half8 qf[5];
#pragma unroll
  for (int e = 0; e < 5; ++e)
    qf[e] = *reinterpret_cast<const half8*>(&Ks[(strip * 32 + m) * KST + e * 16 + h * 8]);
  __syncthreads();  // Q reads done; Ks reusable for K chunks

  // stage chunk-0 K + pe2 (pads 68..87 remain zero; never overwritten)
  for (int c = tid; c < 1024; c += 512) {
    int r = c >> 3, col = (c & 7) * 8;
    *reinterpret_cast<uint4*>(&Ks[r * KST + col]) =
        *reinterpret_cast<const uint4*>(kp + (long)(0 + r) * BE + headoff + col);
  }
  if (tid < 128) {
    long bb = (long)(0 + tid) * 3;
    half4 p2;
    p2[0] = (f16)pe2[bb + 0]; p2[1] = (f16)pe2[bb + 1];
    p2[2] = (f16)pe2[bb + 2]; p2[3] = (f16)0.f;
    *reinterpret_cast<half4*>(&Ks[tid * KST + 64]) = p2;
  }

  floatx16 oacc[2] = {};
  float lpart = 0.f;

#pragma unroll 1
  for (int c = 0; c < NCHUNK; ++c) {
    __syncthreads();  // chunk c staging visible
#pragma unroll
    for (int tt = 0; tt < 2; ++tt) {
      const int t = half * 2 + tt;
      floatx16 st = {};
#pragma unroll
      for (int e = 0; e < 5; ++e) {
        half8 kf = *reinterpret_cast<const half8*>(&Ks[(t * 32 + m) * KST + e * 16 + h * 8]);
        st = __builtin_amdgcn_mfma_f32_32x32x16_f16(kf, qf[e], st, 0, 0, 0);
      }
      float p[16];
#pragma unroll
      for (int r = 0; r < 16; ++r) {
        p[r] = fast_exp2(st[r]);
        lpart += p[r];
      }
#pragma unroll
      for (int s = 0; s < 4; ++s) {
        half2v u0 = pk2(p[4 * s + 0], p[4 * s + 1]);
        half2v u1 = pk2(p[4 * s + 2], p[4 * s + 3]);
        half4 bp;
        bp[0] = u0[0]; bp[1] = u0[1]; bp[2] = u1[0]; bp[3] = u1[1];
        int lcol = t * 32 + s * 8 + h * 4;
#pragma unroll
        for (int dt = 0; dt < 2; ++dt) {
          half4 vf = *reinterpret_cast<const half4*>(&Vt[(dt * 32 + m) * VST + lcol]);
          oacc[dt] = __builtin_amdgcn_mfma_f32_32x32x8f16(vf, bp, oacc[dt], 0, 0, 0);
        }
      }
    }
    __syncthreads();  // all reads of chunk c done
    if (c + 1 < NCHUNK) {
      const int l0 = (c + 1) * 128;
      for (int cc = tid; cc < 1024; cc += 512) {
        int r = cc >> 3, col = (cc & 7) * 8;
        *reinterpret_cast<uint4*>(&Ks[r * KST + col]) =
            *reinterpret_cast<const uint4*>(kp + (long)(l0 + r) * BE + headoff + col);
        int rv = cc >> 4, cv = (cc & 15) * 8;
        *reinterpret_cast<uint4*>(&Vt[rv * VST + cv]) =
            *reinterpret_cast<const uint4*>(vt + vhead + (long)rv * 2048 + l0 + cv);
      }
      if (tid < 128) {
        long bb = (long)(l0 + tid) * 3;
        half4 p2;
        p2[0] = (f16)pe2[bb + 0]; p2[1] = (f16)pe2[bb + 1];
        p2[2] = (f16)pe2[bb + 2]; p2[3] = (f16)0.f;
        *reinterpret_cast<half4*>(&Ks[tid * KST + 64]) = p2;
      }
    }
  }

  // within-wave l reduction: lanes m and m^32 hold same q, disjoint l
  lpart += __shfl_xor(lpart, 32);

  // merge the two l-halves of each strip through LDS (aliases Ks/Vt — safe:
  // last loop barrier already ran, no one reads K/V again)
  if (half == 1) {
    float* dst = comb + (strip * 64 + lane) * 33;
#pragma unroll
    for (int dt = 0; dt < 2; ++dt)
#pragma unroll
      for (int x = 0; x < 16; ++x) dst[dt * 16 + x] = oacc[dt][x];
    dst[32] = lpart;
  }
  __syncthreads();
  if (half == 0) {
    const float* src = comb + (strip * 64 + lane) * 33;
#pragma unroll
    for (int dt = 0; dt < 2; ++dt)
#pragma unroll
      for (int x = 0; x < 16; ++x) oacc[dt][x] += src[dt * 16 + x];
    float inv = 1.f / (lpart + src[32]);
    long qrow = n0 + strip * 32 + m;
#pragma unroll
    for (int dt = 0; dt < 2; ++dt)
#pragma unroll
      for (int g = 0; g < 4; ++g) {
        half4 o4;
#pragma unroll
        for (int x = 0; x < 4; ++x) o4[x] = (f16)(oacc[dt][4 * g + x] * inv);
        int d = dt * 32 + 8 * g + 4 * h;
        *reinterpret_cast<half4*>(ao + qrow * BE + headoff + d) = o4;
      }
  }
}

// ---------------------------------------------------------------------- launch
extern "C" void kernel_launch(void* const* d_in, const int* in_sizes, int n_in,
                              void* d_out, int out_size, void* d_ws, size_t ws_size,
                              hipStream_t stream) {
  const float* q   = (const float*)d_in[0];
  const float* k   = (const float*)d_in[1];
  const float* v   = (const float*)d_in[2];
  const float* pe1 = (const float*)d_in[3];
  const float* pe2 = (const float*)d_in[4];
  const float* Wq  = (const float*)d_in[5];
  const float* bq  = (const float*)d_in[6];
  const float* Wk  = (const float*)d_in[7];
  const float* bk  = (const float*)d_in[8];
  const float* Wv  = (const float*)d_in[9];
  const float* bv  = (const float*)d_in[10];
  const float* Wo  = (const float*)d_in[11];
  const float* bo  = (const float*)d_in[12];
  float* out = (float*)d_out;

  f16* ws = (f16*)d_ws;
  const long TOK = (long)MROWS * EMBED;  // 4,194,304 elements
  f16* qpb = ws;
  f16* kpb = qpb + TOK;
  f16* vtb = kpb + TOK;   // transposed-V (written by gemm_qkv sel==2)
  f16* aob = vtb + TOK;   // ~32 MB total

  gemm_qkv<<<dim3(MROWS / 128, 12), 256, 0, stream>>>(q, k, v, Wq, Wk, Wv,
                                                      bq, bk, bv, qpb, kpb, vtb);

  attn_flash<<<dim3(SEQ_N / 128, BATCH * NHEADS), 512, 0, stream>>>(qpb, kpb, vtb, pe1, pe2, aob);

  gemm_out<<<dim3(MROWS / 128, EMBED / 64), 256, 0, stream>>>(aob, Wo, bo, out);
}

// Round 8
// 203.940 us; speedup vs baseline: 1.2314x; 1.0435x over previous
//
#include <hip/hip_runtime.h>
#include <math.h>

#define EMBED 512
#define HDIM 64
#define NHEADS 8
#define SEQ_N 2048
#define SEQ_L 2048
#define BATCH 4
#define MROWS (SEQ_N*BATCH)   // 8192 rows, row index m = n*BATCH + b
#define BE (BATCH*EMBED)      // 2048 element row stride in (n,b,E) tensors

// scores scale folded into Q-projection and pe1: 1/sqrt(64) * log2(e)
#define QSCALE 0.18033688f

typedef _Float16 f16;
typedef _Float16 half8 __attribute__((ext_vector_type(8)));
typedef _Float16 half4 __attribute__((ext_vector_type(4)));
typedef _Float16 half2v __attribute__((ext_vector_type(2)));
typedef float floatx4 __attribute__((ext_vector_type(4)));
typedef float floatx16 __attribute__((ext_vector_type(16)));

static __device__ inline float fast_exp2(float x) {
#if __has_builtin(__builtin_amdgcn_exp2f)
  return __builtin_amdgcn_exp2f(x);
#else
  return __expf(x * 0.69314718056f);
#endif
}

static __device__ inline half2v pk2(float a, float b) {
#if __has_builtin(__builtin_amdgcn_cvt_pkrtz)
  return __builtin_bit_cast(half2v, __builtin_amdgcn_cvt_pkrtz(a, b));
#else
  half2v o; o[0] = (f16)a; o[1] = (f16)b; return o;
#endif
}

// async global->LDS 16B/lane copy: LDS dest is wave-uniform base + lane*16,
// global src is per-lane. [m97 recipe, width=16]
static __device__ inline void gload16(const void* g, void* l) {
  __builtin_amdgcn_global_load_lds(
      (__attribute__((address_space(1))) void*)(g),
      (__attribute__((address_space(3))) void*)(l), 16, 0, 0);
}

// ---------------------------------------- fused fp32->fp16 converts (1 launch)
// y<3: q/k/v token tensors (TOK elems). y==3: 4 weights, contiguous dst.
__global__ __launch_bounds__(256) void cvt_all(const float* __restrict__ q,
                                               const float* __restrict__ k,
                                               const float* __restrict__ v,
                                               const float* __restrict__ Wq,
                                               const float* __restrict__ Wk,
                                               const float* __restrict__ Wv,
                                               const float* __restrict__ Wo,
                                               f16* __restrict__ qb, f16* __restrict__ kb,
                                               f16* __restrict__ vb, f16* __restrict__ Wb) {
  const long TOK = (long)MROWS * EMBED;
  const long WSZ = (long)EMBED * EMBED;  // 2^18
  int y = blockIdx.y;
  long i = ((long)blockIdx.x * 256 + threadIdx.x) * 4;
  if (y < 3) {
    if (i < TOK) {
      const float* s = y == 0 ? q : y == 1 ? k : v;
      f16* d = y == 0 ? qb : y == 1 ? kb : vb;
      float4 f = *reinterpret_cast<const float4*>(s + i);
      half4 o; o[0] = (f16)f.x; o[1] = (f16)f.y; o[2] = (f16)f.z; o[3] = (f16)f.w;
      *reinterpret_cast<half4*>(d + i) = o;
    }
  } else {
    if (i < 4 * WSZ) {
      int sel = (int)(i >> 18);
      long off = i & (WSZ - 1);
      const float* s = sel == 0 ? Wq : sel == 1 ? Wk : sel == 2 ? Wv : Wo;
      float4 f = *reinterpret_cast<const float4*>(s + off);
      half4 o; o[0] = (f16)f.x; o[1] = (f16)f.y; o[2] = (f16)f.z; o[3] = (f16)f.w;
      *reinterpret_cast<half4*>(Wb + i) = o;
    }
  }
}

// ---------------------------------------- fused QKV projection GEMM (128x128)
// m97-style: async global_load_lds staging (width=16) into UNPADDED 128x32
// f16 tiles, 2-barrier K-loop, no VGPR round-trip. blockIdx.y in [0,12):
// sel = y>>2 picks {q,k,v}; n0 = (y&3)*128. sel==0 output pre-scaled QSCALE;
// sel==2 V stored TRANSPOSED per head into vt[((b*8+h)*64+d)*2048 + l].
__global__ __launch_bounds__(256) void gemm_qkv(const f16* __restrict__ A0,
                                                const f16* __restrict__ A1,
                                                const f16* __restrict__ A2,
                                                const f16* __restrict__ W0,
                                                const f16* __restrict__ W1,
                                                const f16* __restrict__ W2,
                                                const float* __restrict__ b0,
                                                const float* __restrict__ b1,
                                                const float* __restrict__ b2,
                                                f16* __restrict__ C0, f16* __restrict__ C1,
                                                f16* __restrict__ C2t) {
  __shared__ alignas(16) f16 As[128 * 32];
  __shared__ alignas(16) f16 Bs[128 * 32];
  const int sel = blockIdx.y >> 2;
  const f16* A = sel == 0 ? A0 : sel == 1 ? A1 : A2;
  const f16* Bt = sel == 0 ? W0 : sel == 1 ? W1 : W2;
  const float* bias = sel == 0 ? b0 : sel == 1 ? b1 : b2;
  const float scl = sel == 0 ? QSCALE : 1.0f;
  const int tid = threadIdx.x;
  const int wave = tid >> 6, lane = tid & 63, quad = lane >> 4, l16 = lane & 15;
  const int wm = wave & 1, wn = wave >> 1;
  const long m0 = (long)blockIdx.x * 128;
  const long n0 = (long)(blockIdx.y & 3) * 128;
  floatx4 acc[4][4] = {};
  const int srow = lane >> 2;        // 0..15 row within 16-row chunk
  const int scol = (lane & 3) * 8;   // f16 col within 32-wide tile

  for (int k0 = 0; k0 < EMBED; k0 += 32) {
    __syncthreads();
    // wave w stages A rows [w*32, w*32+32) and B rows [w*32, w*32+32)
    gload16(A + (m0 + wave * 32 + srow) * EMBED + k0 + scol, &As[(wave * 32) * 32]);
    gload16(A + (m0 + wave * 32 + 16 + srow) * EMBED + k0 + scol, &As[(wave * 32 + 16) * 32]);
    gload16(Bt + (n0 + wave * 32 + srow) * EMBED + k0 + scol, &Bs[(wave * 32) * 32]);
    gload16(Bt + (n0 + wave * 32 + 16 + srow) * EMBED + k0 + scol, &Bs[(wave * 32 + 16) * 32]);
    __syncthreads();  // compiler emits s_waitcnt vmcnt(0) before this barrier
    half8 af[4], bf[4];
#pragma unroll
    for (int i = 0; i < 4; ++i)
      af[i] = *reinterpret_cast<const half8*>(&As[(wm * 64 + i * 16 + l16) * 32 + quad * 8]);
#pragma unroll
    for (int j = 0; j < 4; ++j)
      bf[j] = *reinterpret_cast<const half8*>(&Bs[(wn * 64 + j * 16 + l16) * 32 + quad * 8]);
#pragma unroll
    for (int i = 0; i < 4; ++i)
#pragma unroll
      for (int j = 0; j < 4; ++j)
        acc[i][j] = __builtin_amdgcn_mfma_f32_16x16x32_f16(af[i], bf[j], acc[i][j], 0, 0, 0);
  }
#pragma unroll
  for (int i = 0; i < 4; ++i)
#pragma unroll
    for (int r = 0; r < 4; ++r) {
      long row = m0 + wm * 64 + i * 16 + quad * 4 + r;
#pragma unroll
      for (int j = 0; j < 4; ++j) {
        long col = n0 + wn * 64 + j * 16 + l16;
        float val = (acc[i][j][r] + bias[col]) * scl;
        if (sel == 2) {
          long bq = row & 3, ltok = row >> 2;
          long hh = col >> 6, dd = col & 63;
          C2t[(((bq << 3) + hh) * 64 + dd) * 2048 + ltok] = (f16)val;
        } else {
          f16* C = sel == 0 ? C0 : C1;
          C[row * EMBED + col] = (f16)val;
        }
      }
    }
}

// ------------------------------ output GEMM (128x64, f16 in, fp32 out, m97-style)
__global__ __launch_bounds__(256) void gemm_out(const f16* __restrict__ A,
                                                const f16* __restrict__ Bt,
                                                const float* __restrict__ bias,
                                                float* __restrict__ C) {
  __shared__ alignas(16) f16 As[128 * 32];
  __shared__ alignas(16) f16 Bs[64 * 32];
  const int tid = threadIdx.x;
  const int wave = tid >> 6, lane = tid & 63, quad = lane >> 4, l16 = lane & 15;
  const long m0 = (long)blockIdx.x * 128;
  const long n0 = (long)blockIdx.y * 64;
  floatx4 acc[2][4] = {};
  const int srow = lane >> 2;
  const int scol = (lane & 3) * 8;

  for (int k0 = 0; k0 < EMBED; k0 += 32) {
    __syncthreads();
    gload16(A + (m0 + wave * 32 + srow) * EMBED + k0 + scol, &As[(wave * 32) * 32]);
    gload16(A + (m0 + wave * 32 + 16 + srow) * EMBED + k0 + scol, &As[(wave * 32 + 16) * 32]);
    gload16(Bt + (n0 + wave * 16 + srow) * EMBED + k0 + scol, &Bs[(wave * 16) * 32]);
    __syncthreads();
    half8 af[2], bf[4];
#pragma unroll
    for (int i = 0; i < 2; ++i)
      af[i] = *reinterpret_cast<const half8*>(&As[(wave * 32 + i * 16 + l16) * 32 + quad * 8]);
#pragma unroll
    for (int j = 0; j < 4; ++j)
      bf[j] = *reinterpret_cast<const half8*>(&Bs[(j * 16 + l16) * 32 + quad * 8]);
#pragma unroll
    for (int i = 0; i < 2; ++i)
#pragma unroll
      for (int j = 0; j < 4; ++j)
        acc[i][j] = __builtin_amdgcn_mfma_f32_16x16x32_f16(af[i], bf[j], acc[i][j], 0, 0, 0);
  }
#pragma unroll
  for (int i = 0; i < 2; ++i)
#pragma unroll
    for (int r = 0; r < 4; ++r) {
      long row = m0 + wave * 32 + i * 16 + quad * 4 + r;
#pragma unroll
      for (int j = 0; j < 4; ++j) {
        long col = n0 + j * 16 + l16;
        C[row * EMBED + col] = acc[i][j][r] + bias[col];
      }
    }
}

// ------------------------------------------------------------- flash attention
// (unchanged from round 7 — 59.2 µs verified)
// grid = (N/128, B*H), 512 threads = 8 waves. Wave-pair (w, w+4) shares the
// q-strip (w&3)*32; half = w>>2 picks l-tiles {0,1} or {2,3} of each chunk.
#define KST 88    // Ks row stride (f16)
#define VST 136   // Vt row stride (f16)
#define NCHUNK (SEQ_L / 128)
#define LDSB (128 * KST * 2 + 64 * VST * 2)   // 39936 B
__global__ __launch_bounds__(512, 4) void attn_flash(const f16* __restrict__ qp,
                                                     const f16* __restrict__ kp,
                                                     const f16* __restrict__ vt,
                                                     const float* __restrict__ pe1,
                                                     const float* __restrict__ pe2,
                                                     f16* __restrict__ ao) {
  __shared__ alignas(16) unsigned char smem[LDSB];
  f16* Ks = reinterpret_cast<f16*>(smem);                       // 128 x KST
  f16* Vt = reinterpret_cast<f16*>(smem + 128 * KST * 2);       // 64 x VST
  float* comb = reinterpret_cast<float*>(smem);                 // merge region
  const int tid = threadIdx.x, wave = tid >> 6, lane = tid & 63;
  const int m = lane & 31, h = lane >> 5;
  const int strip = wave & 3, half = wave >> 2;
  const int n0 = blockIdx.x * 128;
  const int b = blockIdx.y >> 3, hd = blockIdx.y & 7;
  const long headoff = (long)b * EMBED + hd * HDIM;
  const long vhead = (long)blockIdx.y * 64 * 2048;

  for (int c = tid; c < 1024; c += 512) {
    int r = c >> 3, col = (c & 7) * 8;
    *reinterpret_cast<uint4*>(&Ks[r * KST + col]) =
        *reinterpret_cast<const uint4*>(qp + (long)(n0 + r) * BE + headoff + col);
    int rv = c >> 4, cv = (c & 15) * 8;
    *reinterpret_cast<uint4*>(&Vt[rv * VST + cv]) =
        *reinterpret_cast<const uint4*>(vt + vhead + (long)rv * 2048 + 0 + cv);
  }
  {
    const uint4 z4 = {0, 0, 0, 0};
    const uint2 z2 = {0, 0};
    int r = tid >> 2, s = tid & 3;
    if (s == 0) *reinterpret_cast<uint2*>(&Ks[r * KST + 68]) = z2;
    else if (s == 1) *reinterpret_cast<uint4*>(&Ks[r * KST + 72]) = z4;
    else if (s == 2) *reinterpret_cast<uint4*>(&Ks[r * KST + 80]) = z4;
  }
  if (tid < 128) {
    long base = ((long)b * SEQ_N + n0 + tid) * 3;
    half4 v8;
    v8[0] = (f16)(pe1[base + 0] * QSCALE);
    v8[1] = (f16)(pe1[base + 1] * QSCALE);
    v8[2] = (f16)(pe1[base + 2] * QSCALE);
    v8[3] = (f16)0.f;
    *reinterpret_cast<half4*>(&Ks[tid * KST + 64]) = v8;
  }
  __syncthreads();

  half8 qf[5];
#pragma unroll
  for (int e = 0; e < 5; ++e)
    qf[e] = *reinterpret_cast<const half8*>(&Ks[(strip * 32 + m) * KST + e * 16 + h * 8]);
  __syncthreads();  // Q reads done; Ks reusable for K chunks

  for (int c = tid; c < 1024; c += 512) {
    int r = c >> 3, col = (c & 7) * 8;
    *reinterpret_cast<uint4*>(&Ks[r * KST + col]) =
        *reinterpret_cast<const uint4*>(kp + (long)(0 + r) * BE + headoff + col);
  }
  if (tid < 128) {
    long bb = (long)(0 + tid) * 3;
    half4 p2;
    p2[0] = (f16)pe2[bb + 0]; p2[1] = (f16)pe2[bb + 1];
    p2[2] = (f16)pe2[bb + 2]; p2[3] = (f16)0.f;
    *reinterpret_cast<half4*>(&Ks[tid * KST + 64]) = p2;
  }

  floatx16 oacc[2] = {};
  float lpart = 0.f;

#pragma unroll 1
  for (int c = 0; c < NCHUNK; ++c) {
    __syncthreads();
#pragma unroll
    for (int tt = 0; tt < 2; ++tt) {
      const int t = half * 2 + tt;
      floatx16 st = {};
#pragma unroll
      for (int e = 0; e < 5; ++e) {
        half8 kf = *reinterpret_cast<const half8*>(&Ks[(t * 32 + m) * KST + e * 16 + h * 8]);
        st = __builtin_amdgcn_mfma_f32_32x32x16_f16(kf, qf[e], st, 0, 0, 0);
      }
      float p[16];
#pragma unroll
      for (int r = 0; r < 16; ++r) {
        p[r] = fast_exp2(st[r]);
        lpart += p[r];
      }
#pragma unroll
      for (int s = 0; s < 4; ++s) {
        half2v u0 = pk2(p[4 * s + 0], p[4 * s + 1]);
        half2v u1 = pk2(p[4 * s + 2], p[4 * s + 3]);
        half4 bp;
        bp[0] = u0[0]; bp[1] = u0[1]; bp[2] = u1[0]; bp[3] = u1[1];
        int lcol = t * 32 + s * 8 + h * 4;
#pragma unroll
        for (int dt = 0; dt < 2; ++dt) {
          half4 vf = *reinterpret_cast<const half4*>(&Vt[(dt * 32 + m) * VST + lcol]);
          oacc[dt] = __builtin_amdgcn_mfma_f32_32x32x8f16(vf, bp, oacc[dt], 0, 0, 0);
        }
      }
    }
    __syncthreads();
    if (c + 1 < NCHUNK) {
      const int l0 = (c + 1) * 128;
      for (int cc = tid; cc < 1024; cc += 512) {
        int r = cc >> 3, col = (cc & 7) * 8;
        *reinterpret_cast<uint4*>(&Ks[r * KST + col]) =
            *reinterpret_cast<const uint4*>(kp + (long)(l0 + r) * BE + headoff + col);
        int rv = cc >> 4, cv = (cc & 15) * 8;
        *reinterpret_cast<uint4*>(&Vt[rv * VST + cv]) =
            *reinterpret_cast<const uint4*>(vt + vhead + (long)rv * 2048 + l0 + cv);
      }
      if (tid < 128) {
        long bb = (long)(l0 + tid) * 3;
        half4 p2;
        p2[0] = (f16)pe2[bb + 0]; p2[1] = (f16)pe2[bb + 1];
        p2[2] = (f16)pe2[bb + 2]; p2[3] = (f16)0.f;
        *reinterpret_cast<half4*>(&Ks[tid * KST + 64]) = p2;
      }
    }
  }

  lpart += __shfl_xor(lpart, 32);

  if (half == 1) {
    float* dst = comb + (strip * 64 + lane) * 33;
#pragma unroll
    for (int dt = 0; dt < 2; ++dt)
#pragma unroll
      for (int x = 0; x < 16; ++x) dst[dt * 16 + x] = oacc[dt][x];
    dst[32] = lpart;
  }
  __syncthreads();
  if (half == 0) {
    const float* src = comb + (strip * 64 + lane) * 33;
#pragma unroll
    for (int dt = 0; dt < 2; ++dt)
#pragma unroll
      for (int x = 0; x < 16; ++x) oacc[dt][x] += src[dt * 16 + x];
    float inv = 1.f / (lpart + src[32]);
    long qrow = n0 + strip * 32 + m;
#pragma unroll
    for (int dt = 0; dt < 2; ++dt)
#pragma unroll
      for (int g = 0; g < 4; ++g) {
        half4 o4;
#pragma unroll
        for (int x = 0; x < 4; ++x) o4[x] = (f16)(oacc[dt][4 * g + x] * inv);
        int d = dt * 32 + 8 * g + 4 * h;
        *reinterpret_cast<half4*>(ao + qrow * BE + headoff + d) = o4;
      }
  }
}

// ---------------------------------------------------------------------- launch
extern "C" void kernel_launch(void* const* d_in, const int* in_sizes, int n_in,
                              void* d_out, int out_size, void* d_ws, size_t ws_size,
                              hipStream_t stream) {
  const float* q   = (const float*)d_in[0];
  const float* k   = (const float*)d_in[1];
  const float* v   = (const float*)d_in[2];
  const float* pe1 = (const float*)d_in[3];
  const float* pe2 = (const float*)d_in[4];
  const float* Wq  = (const float*)d_in[5];
  const float* bq  = (const float*)d_in[6];
  const float* Wk  = (const float*)d_in[7];
  const float* bk  = (const float*)d_in[8];
  const float* Wv  = (const float*)d_in[9];
  const float* bv  = (const float*)d_in[10];
  const float* Wo  = (const float*)d_in[11];
  const float* bo  = (const float*)d_in[12];
  float* out = (float*)d_out;

  f16* ws = (f16*)d_ws;
  const long TOK = (long)MROWS * EMBED;  // 4,194,304 elements
  const long WSZ = (long)EMBED * EMBED;  //   262,144 elements
  f16* qb  = ws;
  f16* kb  = qb + TOK;
  f16* vb  = kb + TOK;
  f16* Wqb = vb + TOK;          // 4 weights contiguous: Wq,Wk,Wv,Wo
  f16* Wkb = Wqb + WSZ;
  f16* Wvb = Wkb + WSZ;
  f16* Wob = Wvb + WSZ;
  f16* qpb = Wob + WSZ;
  f16* kpb = qpb + TOK;
  f16* vtb = kpb + TOK;         // transposed-V (written by gemm_qkv sel==2)
  f16* aob = vtb + TOK;         // ~61 MB total

  cvt_all<<<dim3(4096, 4), 256, 0, stream>>>(q, k, v, Wq, Wk, Wv, Wo, qb, kb, vb, Wqb);

  gemm_qkv<<<dim3(MROWS / 128, 12), 256, 0, stream>>>(qb, kb, vb, Wqb, Wkb, Wvb,
                                                      bq, bk, bv, qpb, kpb, vtb);

  attn_flash<<<dim3(SEQ_N / 128, BATCH * NHEADS), 512, 0, stream>>>(qpb, kpb, vtb, pe1, pe2, aob);

  gemm_out<<<dim3(MROWS / 128, EMBED / 64), 256, 0, stream>>>(aob, Wob, bo, out);
}